// Round 16
// baseline (1187.267 us; speedup 1.0000x reference)
//
#include <hip/hip_runtime.h>
#include <math.h>

// Residual VQ: x (262144,128) fp32, codebooks (3,256,128) fp32.
// Output: [indices as float (262144*3)] ++ [quantized (262144*128)].
//
// ARITHMETIC CONTRACT (round 3, absmax=0 — do not change):
//   M_k  = OpenBLAS sgemm K-loop: sequential FMA chain j=0..127, acc init 0
//   A    = np.sum(r*r): pairwise_sum 8-accumulator scheme, products rounded
//          separately (fmaf(x,x,0) = single-rounded product, blocks fusion)
//   d2_k = (A - 2.0f*M_k) + B_k ; argmin strict < ascending k
//   residual -= q ; quantized = (q0 + q1) + q2  (elementwise fp32, ref order)
//
// ROUND 20: r18 structure with the r8 REGISTER-ALLOCATION pattern.
// Config matrix: every 512-thread-block config allocates VGPR=64 + spill
// (lb(512,4) x4 rounds, wpe(4,4)); wpe(2,4/2,8) de-spills but pins runtime
// occupancy at 23%. The ONLY no-attr spill-free-high-VGPR datapoint is r8:
// 128-thr blocks + 68.6KB STATIC LDS + lb(128,2) -> VGPR=132. Mechanism:
// the allocator targets LDS-derived achievable occupancy clamped below by
// launch_bounds' min-waves; r8's LDS gives 1 wave/EU < min 2 -> target 2
// -> budget 256 -> no spill. Replicate: kBlock=256 (4 waves), lb(256,2),
// static 67KB LDS -> LDS-derived 2 blocks/CU = 2 waves/EU -> target 2 ->
// budget 256 -> the ~140-reg live set fits. Occupancy ~25% is enough:
// LDS-pipe model 120k b128/CU x ~10.6cyc ~ 530us; VALU ~300us/SIMD with
// 8 independent chains -> 550-750us. Mechanical changes only: staging
// loop 16 iters, 128 items/block, grid x2. DAG identical to r17/r18
// (absmax=0 proven twice).

constexpr int kItems = 262144;
constexpr int kDim   = 128;
constexpr int kNcb   = 3;
constexpr int kK     = 256;
constexpr int kBlock = 256;          // 4 waves; 128 items/block

typedef float f2v __attribute__((ext_vector_type(2)));

__device__ __forceinline__ float sq_rn(float x) {
    return __builtin_fmaf(x, x, 0.0f);   // single-rounded product, blocks contraction
}

// lane L gets lane L-1 within each 16-lane DPP row (row_shr:1, bound_ctrl=1).
// Consumers have o>=1 (L%8!=0 -> L%16!=0), so row boundaries are never read.
__device__ __forceinline__ float dpp_shr1(float v) {
    int r = __builtin_amdgcn_update_dpp(
        0, __builtin_bit_cast(int, v), 0x111 /*row_shr:1*/, 0xf, 0xf, true);
    return __builtin_bit_cast(float, r);
}

// packed FMA (HW-verified r16): per-half fmaf. PK_LO broadcasts C.lo to both
// result halves; PK_HI broadcasts C.hi.
#define PK_LO(M, P, C) asm("v_pk_fma_f32 %0, %1, %2, %0 op_sel:[0,0,0] op_sel_hi:[1,0,1]" \
                           : "+v"(M) : "v"(P), "v"(C));
#define PK_HI(M, P, C) asm("v_pk_fma_f32 %0, %1, %2, %0 op_sel:[0,1,0] op_sel_hi:[1,1,1]" \
                           : "+v"(M) : "v"(P), "v"(C));

// ONLY for codebook B_k staging (global reads)
__device__ __forceinline__ float np_sumsq128(const float* __restrict__ p) {
    float a0 = sq_rn(p[0]), a1 = sq_rn(p[1]), a2 = sq_rn(p[2]), a3 = sq_rn(p[3]),
          a4 = sq_rn(p[4]), a5 = sq_rn(p[5]), a6 = sq_rn(p[6]), a7 = sq_rn(p[7]);
    #pragma unroll
    for (int i = 8; i < 128; i += 8) {
        a0 = a0 + sq_rn(p[i + 0]); a1 = a1 + sq_rn(p[i + 1]);
        a2 = a2 + sq_rn(p[i + 2]); a3 = a3 + sq_rn(p[i + 3]);
        a4 = a4 + sq_rn(p[i + 4]); a5 = a5 + sq_rn(p[i + 5]);
        a6 = a6 + sq_rn(p[i + 6]); a7 = a7 + sq_rn(p[i + 7]);
    }
    return ((a0 + a1) + (a2 + a3)) + ((a4 + a5) + (a6 + a7));
}

// ---- residual: 16 local dims (16o..16o+15) x 2 packed pairs: PAB_j=(A_j,B_j),
// PCD_j=(C_j,D_j). 32 named f2v = 64 VGPR hot set.
#define D16(P) f2v P##0,P##1,P##2,P##3,P##4,P##5,P##6,P##7, \
                   P##8,P##9,P##10,P##11,P##12,P##13,P##14,P##15;

#define LOADP() { \
  { const float4 a_=xa4[0], b_=xb4[0], c_=xc4[0], d_=xd4[0]; \
    PAB0=(f2v){a_.x,b_.x}; PAB1=(f2v){a_.y,b_.y}; PAB2=(f2v){a_.z,b_.z}; PAB3=(f2v){a_.w,b_.w}; \
    PCD0=(f2v){c_.x,d_.x}; PCD1=(f2v){c_.y,d_.y}; PCD2=(f2v){c_.z,d_.z}; PCD3=(f2v){c_.w,d_.w}; } \
  { const float4 a_=xa4[1], b_=xb4[1], c_=xc4[1], d_=xd4[1]; \
    PAB4=(f2v){a_.x,b_.x}; PAB5=(f2v){a_.y,b_.y}; PAB6=(f2v){a_.z,b_.z}; PAB7=(f2v){a_.w,b_.w}; \
    PCD4=(f2v){c_.x,d_.x}; PCD5=(f2v){c_.y,d_.y}; PCD6=(f2v){c_.z,d_.z}; PCD7=(f2v){c_.w,d_.w}; } \
  { const float4 a_=xa4[2], b_=xb4[2], c_=xc4[2], d_=xd4[2]; \
    PAB8=(f2v){a_.x,b_.x}; PAB9=(f2v){a_.y,b_.y}; PAB10=(f2v){a_.z,b_.z}; PAB11=(f2v){a_.w,b_.w}; \
    PCD8=(f2v){c_.x,d_.x}; PCD9=(f2v){c_.y,d_.y}; PCD10=(f2v){c_.z,d_.z}; PCD11=(f2v){c_.w,d_.w}; } \
  { const float4 a_=xa4[3], b_=xb4[3], c_=xc4[3], d_=xd4[3]; \
    PAB12=(f2v){a_.x,b_.x}; PAB13=(f2v){a_.y,b_.y}; PAB14=(f2v){a_.z,b_.z}; PAB15=(f2v){a_.w,b_.w}; \
    PCD12=(f2v){c_.x,d_.x}; PCD13=(f2v){c_.y,d_.y}; PCD14=(f2v){c_.z,d_.z}; PCD15=(f2v){c_.w,d_.w}; } }

// A = np.sum(r*r) pairwise-8: local j=4u+e -> acc (4u+e)&7 ((16o)%8==0), j asc
#define SQ2(P) ((f2v){sq_rn((P).x), sq_rn((P).y)})
#define AFOLDP(P) \
  U0+=SQ2(P##0);  U1+=SQ2(P##1);  U2+=SQ2(P##2);  U3+=SQ2(P##3); \
  U4+=SQ2(P##4);  U5+=SQ2(P##5);  U6+=SQ2(P##6);  U7+=SQ2(P##7); \
  U0+=SQ2(P##8);  U1+=SQ2(P##9);  U2+=SQ2(P##10); U3+=SQ2(P##11); \
  U4+=SQ2(P##12); U5+=SQ2(P##13); U6+=SQ2(P##14); U7+=SQ2(P##15);
#define ASHFLP() \
  U0.x=dpp_shr1(U0.x); U0.y=dpp_shr1(U0.y); U1.x=dpp_shr1(U1.x); U1.y=dpp_shr1(U1.y); \
  U2.x=dpp_shr1(U2.x); U2.y=dpp_shr1(U2.y); U3.x=dpp_shr1(U3.x); U3.y=dpp_shr1(U3.y); \
  U4.x=dpp_shr1(U4.x); U4.y=dpp_shr1(U4.y); U5.x=dpp_shr1(U5.x); U5.y=dpp_shr1(U5.y); \
  U6.x=dpp_shr1(U6.x); U6.y=dpp_shr1(U6.y); U7.x=dpp_shr1(U7.x); U7.y=dpp_shr1(U7.y);
// 8-round serial handoff along o (exact left fold); valid at o==7.
#define ACOMPUTEP(P, A1, A2) { \
  f2v U0={0.f,0.f},U1={0.f,0.f},U2={0.f,0.f},U3={0.f,0.f}, \
      U4={0.f,0.f},U5={0.f,0.f},U6={0.f,0.f},U7={0.f,0.f}; \
  if (o == 0) { AFOLDP(P) } \
  ASHFLP() if (o == 1) { AFOLDP(P) } \
  ASHFLP() if (o == 2) { AFOLDP(P) } \
  ASHFLP() if (o == 3) { AFOLDP(P) } \
  ASHFLP() if (o == 4) { AFOLDP(P) } \
  ASHFLP() if (o == 5) { AFOLDP(P) } \
  ASHFLP() if (o == 6) { AFOLDP(P) } \
  ASHFLP() if (o == 7) { AFOLDP(P) } \
  const f2v AP_ = ((U0 + U1) + (U2 + U3)) + ((U4 + U5) + (U6 + U7)); \
  A1 = AP_.x; A2 = AP_.y; }

// one tile row rr: 4 shared ds_read_b128 (16 dims) feed 4 items = 32 pk_fma.
// c_q at offset q*8 holds dims 16o+4q..+3 (layout slot=row*32+(cc&3)*8+(cc>>2)).
// Per chain: q ascending, e ascending within q -> ascending local j.
#define FOLDROW(rr) { \
  const float4 c0_=tcr[(rr)*32+0], c1_=tcr[(rr)*32+8], c2_=tcr[(rr)*32+16], c3_=tcr[(rr)*32+24]; \
  const f2v c0l={c0_.x,c0_.y}, c0h={c0_.z,c0_.w}, c1l={c1_.x,c1_.y}, c1h={c1_.z,c1_.w}, \
            c2l={c2_.x,c2_.y}, c2h={c2_.z,c2_.w}, c3l={c3_.x,c3_.y}, c3h={c3_.z,c3_.w}; \
  PK_LO(mAB##rr,PAB0,c0l)  PK_HI(mAB##rr,PAB1,c0l)  PK_LO(mAB##rr,PAB2,c0h)  PK_HI(mAB##rr,PAB3,c0h) \
  PK_LO(mAB##rr,PAB4,c1l)  PK_HI(mAB##rr,PAB5,c1l)  PK_LO(mAB##rr,PAB6,c1h)  PK_HI(mAB##rr,PAB7,c1h) \
  PK_LO(mAB##rr,PAB8,c2l)  PK_HI(mAB##rr,PAB9,c2l)  PK_LO(mAB##rr,PAB10,c2h) PK_HI(mAB##rr,PAB11,c2h) \
  PK_LO(mAB##rr,PAB12,c3l) PK_HI(mAB##rr,PAB13,c3l) PK_LO(mAB##rr,PAB14,c3h) PK_HI(mAB##rr,PAB15,c3h) \
  PK_LO(mCD##rr,PCD0,c0l)  PK_HI(mCD##rr,PCD1,c0l)  PK_LO(mCD##rr,PCD2,c0h)  PK_HI(mCD##rr,PCD3,c0h) \
  PK_LO(mCD##rr,PCD4,c1l)  PK_HI(mCD##rr,PCD5,c1l)  PK_LO(mCD##rr,PCD6,c1h)  PK_HI(mCD##rr,PCD7,c1h) \
  PK_LO(mCD##rr,PCD8,c2l)  PK_HI(mCD##rr,PCD9,c2l)  PK_LO(mCD##rr,PCD10,c2h) PK_HI(mCD##rr,PCD11,c2h) \
  PK_LO(mCD##rr,PCD12,c3l) PK_HI(mCD##rr,PCD13,c3l) PK_LO(mCD##rr,PCD14,c3h) PK_HI(mCD##rr,PCD15,c3h) }

// residual -= q (elementwise, ref order): this lane's 16 dims of all 4 items
#define SUBP() { \
  { const float4 a_=cwA[0], b_=cwB[0], c_=cwC[0], d_=cwD[0]; \
    PAB0.x-=a_.x; PAB0.y-=b_.x; PAB1.x-=a_.y; PAB1.y-=b_.y; \
    PAB2.x-=a_.z; PAB2.y-=b_.z; PAB3.x-=a_.w; PAB3.y-=b_.w; \
    PCD0.x-=c_.x; PCD0.y-=d_.x; PCD1.x-=c_.y; PCD1.y-=d_.y; \
    PCD2.x-=c_.z; PCD2.y-=d_.z; PCD3.x-=c_.w; PCD3.y-=d_.w; } \
  { const float4 a_=cwA[1], b_=cwB[1], c_=cwC[1], d_=cwD[1]; \
    PAB4.x-=a_.x; PAB4.y-=b_.x; PAB5.x-=a_.y; PAB5.y-=b_.y; \
    PAB6.x-=a_.z; PAB6.y-=b_.z; PAB7.x-=a_.w; PAB7.y-=b_.w; \
    PCD4.x-=c_.x; PCD4.y-=d_.x; PCD5.x-=c_.y; PCD5.y-=d_.y; \
    PCD6.x-=c_.z; PCD6.y-=d_.z; PCD7.x-=c_.w; PCD7.y-=d_.w; } \
  { const float4 a_=cwA[2], b_=cwB[2], c_=cwC[2], d_=cwD[2]; \
    PAB8.x-=a_.x;  PAB8.y-=b_.x;  PAB9.x-=a_.y;  PAB9.y-=b_.y; \
    PAB10.x-=a_.z; PAB10.y-=b_.z; PAB11.x-=a_.w; PAB11.y-=b_.w; \
    PCD8.x-=c_.x;  PCD8.y-=d_.x;  PCD9.x-=c_.y;  PCD9.y-=d_.y; \
    PCD10.x-=c_.z; PCD10.y-=d_.z; PCD11.x-=c_.w; PCD11.y-=d_.w; } \
  { const float4 a_=cwA[3], b_=cwB[3], c_=cwC[3], d_=cwD[3]; \
    PAB12.x-=a_.x; PAB12.y-=b_.x; PAB13.x-=a_.y; PAB13.y-=b_.y; \
    PAB14.x-=a_.z; PAB14.y-=b_.z; PAB15.x-=a_.w; PAB15.y-=b_.w; \
    PCD12.x-=c_.x; PCD12.y-=d_.x; PCD13.x-=c_.y; PCD13.y-=d_.y; \
    PCD14.x-=c_.z; PCD14.y-=d_.z; PCD15.x-=c_.w; PCD15.y-=d_.w; } }

// quantized output: ((0+q0)+q1)+q2, fp32 elementwise, lane's 16 dims
#define OUTQ(s0v, s1v, s2v, itemv) { \
  const float4* g0_ = (const float4*)(cb + ((size_t)0 * kK + (s0v)) * kDim) + o * 4; \
  const float4* g1_ = (const float4*)(cb + ((size_t)1 * kK + (s1v)) * kDim) + o * 4; \
  const float4* g2_ = (const float4*)(cb + ((size_t)2 * kK + (s2v)) * kDim) + o * 4; \
  float4* qo_ = (float4*)(out_q + (itemv) * kDim) + o * 4; \
  _Pragma("unroll") \
  for (int u = 0; u < 4; ++u) { \
    const float4 v0 = g0_[u], v1 = g1_[u], v2 = g2_[u]; \
    float4 w_; \
    w_.x=(v0.x+v1.x)+v2.x; w_.y=(v0.y+v1.y)+v2.y; \
    w_.z=(v0.z+v1.z)+v2.z; w_.w=(v0.w+v1.w)+v2.w; \
    qo_[u]=w_; } }

__global__ __launch_bounds__(kBlock, 2) void rvq_kernel(
    const float* __restrict__ x,
    const float* __restrict__ cb,
    float* __restrict__ out)
{
    // r8 allocation pattern: big STATIC LDS + small block + low min-waves.
    // LDS-derived occupancy (2 blocks/CU = 2 waves/EU) >= min 2 -> RA
    // targets 2 waves/EU -> budget 256 VGPR -> ~140-reg live set fits.
    __shared__ float4 s_cb[4096];           // 64 KiB: one phase,
                                            // slot = row*32 + (cc&3)*8 + (cc>>2)
    __shared__ float4 s_B4[kNcb * kK / 4];  // 3 KiB

    const int tid  = threadIdx.x;
    const int lane = tid & 63;
    const int o    = lane & 7;              // dim-eighth 0..7
    const int grp  = lane >> 3;             // item-group 0..7 (4 items each)
    const int wave = tid >> 6;              // 0..3

    // B_k = np.sum(cb*cb, axis=-1), bit-exact
    for (int m = tid; m < kNcb * kK; m += kBlock)
        ((float*)s_B4)[m] = np_sumsq128(cb + (size_t)m * kDim);

    const size_t iA = (size_t)blockIdx.x * 128 + wave * 32 + grp * 4 + 0;
    const size_t iB = iA + 1, iC = iA + 2, iD = iA + 3;
    const float4* xa4 = (const float4*)(x + iA * kDim) + o * 4;
    const float4* xb4 = (const float4*)(x + iB * kDim) + o * 4;
    const float4* xc4 = (const float4*)(x + iC * kDim) + o * 4;
    const float4* xd4 = (const float4*)(x + iD * kDim) + o * 4;

    D16(PAB) D16(PCD)
    LOADP()

    float Aa, Ab, Ac, Ad;
    ACOMPUTEP(PAB, Aa, Ab)
    ACOMPUTEP(PCD, Ac, Ad)

    int sA0=0,sA1=0,sA2=0,sB0=0,sB1=0,sB2=0,sC0=0,sC1=0,sC2=0,sD0=0,sD1=0,sD2=0;

    #pragma unroll
    for (int c = 0; c < kNcb; ++c) {
        float bestA = INFINITY, bestB = INFINITY, bestC = INFINITY, bestD = INFINITY;
        int   biA = 0, biB = 0, biC = 0, biD = 0;

        #pragma unroll
        for (int ph = 0; ph < 2; ++ph) {
            __syncthreads();   // previous phase fully consumed
            // stage 128 rows: linear coalesced global read, permuted LDS write
            // (4096 float4 with 256 threads -> 16 iterations)
            {
                const float4* gsrc = (const float4*)cb + ((size_t)(c * kK + ph * 128)) * 32;
                #pragma unroll
                for (int u = 0; u < 16; ++u) {
                    const int gi  = u * kBlock + tid;
                    const int row = gi >> 5, cc = gi & 31;
                    s_cb[row * 32 + (cc & 3) * 8 + (cc >> 2)] = gsrc[gi];
                }
            }
            __syncthreads();

            const int kbase = ph * 128;
            const int cb64  = c * 64 + ph * 32;
            f2v vmAB0={0.f,0.f},vmAB1={0.f,0.f},vmAB2={0.f,0.f},vmAB3={0.f,0.f};
            f2v vmCD0={0.f,0.f},vmCD1={0.f,0.f},vmCD2={0.f,0.f},vmCD3={0.f,0.f};

            // depth-8 pipeline: lane o works group g-o; finals at o==7, g>=7
            #pragma unroll 1
            for (int g = 0; g < 39; ++g) {
                int gg = g - o; gg = gg < 0 ? 0 : (gg > 31 ? 31 : gg);
                const float4* tcr = s_cb + gg * 128 + o;
                f2v mAB0 = o ? vmAB0 : (f2v){0.f,0.f}, mAB1 = o ? vmAB1 : (f2v){0.f,0.f},
                    mAB2 = o ? vmAB2 : (f2v){0.f,0.f}, mAB3 = o ? vmAB3 : (f2v){0.f,0.f};
                f2v mCD0 = o ? vmCD0 : (f2v){0.f,0.f}, mCD1 = o ? vmCD1 : (f2v){0.f,0.f},
                    mCD2 = o ? vmCD2 : (f2v){0.f,0.f}, mCD3 = o ? vmCD3 : (f2v){0.f,0.f};
                FOLDROW(0) FOLDROW(1) FOLDROW(2) FOLDROW(3)
                if (o == 7 && g >= 7) {
                    const int gf = g - 7;
                    const float4 bb = s_B4[cb64 + gf];
                    const int kb = kbase + gf * 4;
                    float d_;
                    d_=(Aa-2.0f*mAB0.x)+bb.x; if(d_<bestA){bestA=d_;biA=kb+0;}
                    d_=(Aa-2.0f*mAB1.x)+bb.y; if(d_<bestA){bestA=d_;biA=kb+1;}
                    d_=(Aa-2.0f*mAB2.x)+bb.z; if(d_<bestA){bestA=d_;biA=kb+2;}
                    d_=(Aa-2.0f*mAB3.x)+bb.w; if(d_<bestA){bestA=d_;biA=kb+3;}
                    d_=(Ab-2.0f*mAB0.y)+bb.x; if(d_<bestB){bestB=d_;biB=kb+0;}
                    d_=(Ab-2.0f*mAB1.y)+bb.y; if(d_<bestB){bestB=d_;biB=kb+1;}
                    d_=(Ab-2.0f*mAB2.y)+bb.z; if(d_<bestB){bestB=d_;biB=kb+2;}
                    d_=(Ab-2.0f*mAB3.y)+bb.w; if(d_<bestB){bestB=d_;biB=kb+3;}
                    d_=(Ac-2.0f*mCD0.x)+bb.x; if(d_<bestC){bestC=d_;biC=kb+0;}
                    d_=(Ac-2.0f*mCD1.x)+bb.y; if(d_<bestC){bestC=d_;biC=kb+1;}
                    d_=(Ac-2.0f*mCD2.x)+bb.z; if(d_<bestC){bestC=d_;biC=kb+2;}
                    d_=(Ac-2.0f*mCD3.x)+bb.w; if(d_<bestC){bestC=d_;biC=kb+3;}
                    d_=(Ad-2.0f*mCD0.y)+bb.x; if(d_<bestD){bestD=d_;biD=kb+0;}
                    d_=(Ad-2.0f*mCD1.y)+bb.y; if(d_<bestD){bestD=d_;biD=kb+1;}
                    d_=(Ad-2.0f*mCD2.y)+bb.z; if(d_<bestD){bestD=d_;biD=kb+2;}
                    d_=(Ad-2.0f*mCD3.y)+bb.w; if(d_<bestD){bestD=d_;biD=kb+3;}
                }
                vmAB0.x=dpp_shr1(mAB0.x); vmAB0.y=dpp_shr1(mAB0.y);
                vmAB1.x=dpp_shr1(mAB1.x); vmAB1.y=dpp_shr1(mAB1.y);
                vmAB2.x=dpp_shr1(mAB2.x); vmAB2.y=dpp_shr1(mAB2.y);
                vmAB3.x=dpp_shr1(mAB3.x); vmAB3.y=dpp_shr1(mAB3.y);
                vmCD0.x=dpp_shr1(mCD0.x); vmCD0.y=dpp_shr1(mCD0.y);
                vmCD1.x=dpp_shr1(mCD1.x); vmCD1.y=dpp_shr1(mCD1.y);
                vmCD2.x=dpp_shr1(mCD2.x); vmCD2.y=dpp_shr1(mCD2.y);
                vmCD3.x=dpp_shr1(mCD3.x); vmCD3.y=dpp_shr1(mCD3.y);
            }
        }

        const int selA = __shfl(biA, lane | 7);   // broadcast from o==7
        const int selB = __shfl(biB, lane | 7);
        const int selC = __shfl(biC, lane | 7);
        const int selD = __shfl(biD, lane | 7);
        if (c == 0)      { sA0=selA; sB0=selB; sC0=selC; sD0=selD; }
        else if (c == 1) { sA1=selA; sB1=selB; sC1=selC; sD1=selD; }
        else             { sA2=selA; sB2=selB; sC2=selC; sD2=selD; }

        if (c < kNcb - 1) {
            const float4* cwA = (const float4*)(cb + ((size_t)c*kK + selA)*kDim) + o*4;
            const float4* cwB = (const float4*)(cb + ((size_t)c*kK + selB)*kDim) + o*4;
            const float4* cwC = (const float4*)(cb + ((size_t)c*kK + selC)*kDim) + o*4;
            const float4* cwD = (const float4*)(cb + ((size_t)c*kK + selD)*kDim) + o*4;
            SUBP()
            ACOMPUTEP(PAB, Aa, Ab)
            ACOMPUTEP(PCD, Ac, Ad)
        }
    }

    // ---- outputs
    float* out_idx = out;                             // (items, 3) as float
    float* out_q   = out + (size_t)kItems * kNcb;     // (items, 128)
    if (o == 0) {
        out_idx[iA*3+0]=(float)sA0; out_idx[iA*3+1]=(float)sA1; out_idx[iA*3+2]=(float)sA2;
        out_idx[iB*3+0]=(float)sB0; out_idx[iB*3+1]=(float)sB1; out_idx[iB*3+2]=(float)sB2;
        out_idx[iC*3+0]=(float)sC0; out_idx[iC*3+1]=(float)sC1; out_idx[iC*3+2]=(float)sC2;
        out_idx[iD*3+0]=(float)sD0; out_idx[iD*3+1]=(float)sD1; out_idx[iD*3+2]=(float)sD2;
    }
    OUTQ(sA0, sA1, sA2, iA)
    OUTQ(sB0, sB1, sB2, iB)
    OUTQ(sC0, sC1, sC2, iC)
    OUTQ(sD0, sD1, sD2, iD)
}

extern "C" void kernel_launch(void* const* d_in, const int* in_sizes, int n_in,
                              void* d_out, int out_size, void* d_ws, size_t ws_size,
                              hipStream_t stream) {
    const float* x  = (const float*)d_in[0];
    const float* cb = (const float*)d_in[1];
    float* out = (float*)d_out;
    rvq_kernel<<<kItems / 128, kBlock, 0, stream>>>(x, cb, out);
}

// Round 17
// 970.676 us; speedup vs baseline: 1.2231x; 1.2231x over previous
//
#include <hip/hip_runtime.h>
#include <math.h>

// Residual VQ: x (262144,128) fp32, codebooks (3,256,128) fp32.
// Output: [indices as float (262144*3)] ++ [quantized (262144*128)].
//
// ARITHMETIC CONTRACT (round 3, absmax=0 — do not change):
//   M_k  = OpenBLAS sgemm K-loop: sequential FMA chain j=0..127, acc init 0
//   A    = np.sum(r*r): pairwise_sum 8-accumulator scheme, products rounded
//          separately (fmaf(x,x,0) = single-rounded product, blocks fusion)
//   d2_k = (A - 2.0f*M_k) + B_k ; argmin strict < ascending k
//   residual -= q ; quantized = (q0 + q1) + q2  (elementwise fp32, ref order)
//
// ROUND 21: RESTORE THE r16 CHAMPION (880us steady / 973 reported).
// r20 closed the investigation: spill-free 4-item structure (VGPR 120,
// WRITE 135MB clean) measured 1203us because its VALU ISSUE is 835us/SIMD
// vs r16's 616us — duration is bounded below by issue time, so the 4-item
// family cannot beat r16 regardless of occupancy. The r16 structure is
// dual-pipe saturated (LDS ~93% of per-CU ceiling AND VALU 70%, measured);
// every departure tried this session (4-item sharing x2, eighth-split,
// spill-free-low-occupancy x4, waves_per_eu x4, LDS-resident residual,
// split-lane chains) measured worse. Its VGPR-64 spill is an RA artifact
// that no config knob removed without costing more than it saved.
// Structure: 2 items/lane packed in v_pk_fma_f32 (op_sel broadcast),
// quarter-dim split with depth-4 DPP row_shr:1 left-fold handoff (VALU
// pipe, not LDS), 64KB codebook phase staging, 512-thr launch_bounds(512,4).

constexpr int kItems = 262144;
constexpr int kDim   = 128;
constexpr int kNcb   = 3;
constexpr int kK     = 256;
constexpr int kBlock = 512;          // 8 waves; 256 items/block

typedef float f2v __attribute__((ext_vector_type(2)));

__device__ __forceinline__ float sq_rn(float x) {
    return __builtin_fmaf(x, x, 0.0f);   // single-rounded product, blocks contraction
}

// lane L gets lane L-1 within each 16-lane DPP row (row_shr:1, bound_ctrl=1).
// Consumers are q>=1 (L%4!=0 -> L%16!=0), so row boundaries are never read.
__device__ __forceinline__ float dpp_shr1(float v) {
    int r = __builtin_amdgcn_update_dpp(
        0, __builtin_bit_cast(int, v), 0x111 /*row_shr:1*/, 0xf, 0xf, true);
    return __builtin_bit_cast(float, r);
}

// packed FMA: M.lo += P.lo * C.sel ; M.hi += P.hi * C.sel  (per-half fmaf).
// PK_LO uses C's LOW half for both result halves; PK_HI uses C's HIGH half.
#define PK_LO(M, P, C) asm("v_pk_fma_f32 %0, %1, %2, %0 op_sel:[0,0,0] op_sel_hi:[1,0,1]" \
                           : "+v"(M) : "v"(P), "v"(C));
#define PK_HI(M, P, C) asm("v_pk_fma_f32 %0, %1, %2, %0 op_sel:[0,1,0] op_sel_hi:[1,1,1]" \
                           : "+v"(M) : "v"(P), "v"(C));

// ONLY for codebook B_k staging (global reads)
__device__ __forceinline__ float np_sumsq128(const float* __restrict__ p) {
    float a0 = sq_rn(p[0]), a1 = sq_rn(p[1]), a2 = sq_rn(p[2]), a3 = sq_rn(p[3]),
          a4 = sq_rn(p[4]), a5 = sq_rn(p[5]), a6 = sq_rn(p[6]), a7 = sq_rn(p[7]);
    #pragma unroll
    for (int i = 8; i < 128; i += 8) {
        a0 = a0 + sq_rn(p[i + 0]); a1 = a1 + sq_rn(p[i + 1]);
        a2 = a2 + sq_rn(p[i + 2]); a3 = a3 + sq_rn(p[i + 3]);
        a4 = a4 + sq_rn(p[i + 4]); a5 = a5 + sq_rn(p[i + 5]);
        a6 = a6 + sq_rn(p[i + 6]); a7 = a7 + sq_rn(p[i + 7]);
    }
    return ((a0 + a1) + (a2 + a3)) + ((a4 + a5) + (a6 + a7));
}

// ---- residual: 32 packed pairs PRj = (itemA dim j', itemB dim j'), j'=q*32+j
#define PLIST(M) M(0) M(1) M(2) M(3) M(4) M(5) M(6) M(7) \
  M(8) M(9) M(10) M(11) M(12) M(13) M(14) M(15) \
  M(16) M(17) M(18) M(19) M(20) M(21) M(22) M(23) \
  M(24) M(25) M(26) M(27) M(28) M(29) M(30) M(31)
#define DECLP(j) f2v PR##j;

#define ULIST(M) M(0,0,1,2,3) M(1,4,5,6,7) M(2,8,9,10,11) M(3,12,13,14,15) \
  M(4,16,17,18,19) M(5,20,21,22,23) M(6,24,25,26,27) M(7,28,29,30,31)

#define LOADU(u,j0,j1,j2,j3) { const float4 a_ = xa4[u], b_ = xb4[u]; \
  PR##j0 = (f2v){a_.x, b_.x}; PR##j1 = (f2v){a_.y, b_.y}; \
  PR##j2 = (f2v){a_.z, b_.z}; PR##j3 = (f2v){a_.w, b_.w}; }

#define SUBU(u,j0,j1,j2,j3) { const float4 a_ = cwA[u], b_ = cwB[u]; \
  PR##j0.x -= a_.x; PR##j0.y -= b_.x; PR##j1.x -= a_.y; PR##j1.y -= b_.y; \
  PR##j2.x -= a_.z; PR##j2.y -= b_.z; PR##j3.x -= a_.w; PR##j3.y -= b_.w; }

// A = np.sum(r*r) both items at once: term j' -> acc (j'&7), j' ascending.
#define SQ2(P) ((f2v){sq_rn((P).x), sq_rn((P).y)})
#define AFOLDALL() \
  U0+=SQ2(PR0);  U1+=SQ2(PR1);  U2+=SQ2(PR2);  U3+=SQ2(PR3); \
  U4+=SQ2(PR4);  U5+=SQ2(PR5);  U6+=SQ2(PR6);  U7+=SQ2(PR7); \
  U0+=SQ2(PR8);  U1+=SQ2(PR9);  U2+=SQ2(PR10); U3+=SQ2(PR11); \
  U4+=SQ2(PR12); U5+=SQ2(PR13); U6+=SQ2(PR14); U7+=SQ2(PR15); \
  U0+=SQ2(PR16); U1+=SQ2(PR17); U2+=SQ2(PR18); U3+=SQ2(PR19); \
  U4+=SQ2(PR20); U5+=SQ2(PR21); U6+=SQ2(PR22); U7+=SQ2(PR23); \
  U0+=SQ2(PR24); U1+=SQ2(PR25); U2+=SQ2(PR26); U3+=SQ2(PR27); \
  U4+=SQ2(PR28); U5+=SQ2(PR29); U6+=SQ2(PR30); U7+=SQ2(PR31);
#define ASHFLP() \
  U0.x=dpp_shr1(U0.x); U0.y=dpp_shr1(U0.y); U1.x=dpp_shr1(U1.x); U1.y=dpp_shr1(U1.y); \
  U2.x=dpp_shr1(U2.x); U2.y=dpp_shr1(U2.y); U3.x=dpp_shr1(U3.x); U3.y=dpp_shr1(U3.y); \
  U4.x=dpp_shr1(U4.x); U4.y=dpp_shr1(U4.y); U5.x=dpp_shr1(U5.x); U5.y=dpp_shr1(U5.y); \
  U6.x=dpp_shr1(U6.x); U6.y=dpp_shr1(U6.y); U7.x=dpp_shr1(U7.x); U7.y=dpp_shr1(U7.y);
// 4-round serial handoff along q (exact left fold); valid at q==3.
#define ACOMPUTE() { \
  f2v U0={0.f,0.f},U1={0.f,0.f},U2={0.f,0.f},U3={0.f,0.f}, \
      U4={0.f,0.f},U5={0.f,0.f},U6={0.f,0.f},U7={0.f,0.f}; \
  if (q == 0) { AFOLDALL() } \
  ASHFLP() if (q == 1) { AFOLDALL() } \
  ASHFLP() if (q == 2) { AFOLDALL() } \
  ASHFLP() if (q == 3) { AFOLDALL() } \
  const f2v AP_ = ((U0 + U1) + (U2 + U3)) + ((U4 + U5) + (U6 + U7)); \
  Aa = AP_.x; Ab = AP_.y; }

// one quad column u: 4 ds_read_b128 (rows kb..kb+3) feed 2 items x 16 FMAs
// as 16 pk_fma. Per row r chain m_r: e ascending (c.x,c.y,c.z,c.w), u
// ascending across calls -> per-chain order = ascending local j'.
#define FOLD_U(u, Pa, Pb, Pc, Pd) { \
  const float4 c0_ = tc[      (u)*4]; \
  const float4 c1_ = tc[32 + (u)*4]; \
  const float4 c2_ = tc[64 + (u)*4]; \
  const float4 c3_ = tc[96 + (u)*4]; \
  const f2v c0lo = {c0_.x, c0_.y}, c0hi = {c0_.z, c0_.w}; \
  const f2v c1lo = {c1_.x, c1_.y}, c1hi = {c1_.z, c1_.w}; \
  const f2v c2lo = {c2_.x, c2_.y}, c2hi = {c2_.z, c2_.w}; \
  const f2v c3lo = {c3_.x, c3_.y}, c3hi = {c3_.z, c3_.w}; \
  PK_LO(m0, Pa, c0lo) PK_HI(m0, Pb, c0lo) PK_LO(m0, Pc, c0hi) PK_HI(m0, Pd, c0hi) \
  PK_LO(m1, Pa, c1lo) PK_HI(m1, Pb, c1lo) PK_LO(m1, Pc, c1hi) PK_HI(m1, Pd, c1hi) \
  PK_LO(m2, Pa, c2lo) PK_HI(m2, Pb, c2lo) PK_LO(m2, Pc, c2hi) PK_HI(m2, Pd, c2hi) \
  PK_LO(m3, Pa, c3lo) PK_HI(m3, Pb, c3lo) PK_LO(m3, Pc, c3hi) PK_HI(m3, Pd, c3hi) }

__global__ __launch_bounds__(kBlock, 4) void rvq_kernel(
    const float* __restrict__ x,
    const float* __restrict__ cb,
    float* __restrict__ out)
{
    extern __shared__ float4 s_cb[];        // 4096 float4 = 64 KiB (one phase,
                                            // layout [row128][jq8][q4])
    __shared__ float4 s_B4[kNcb * kK / 4];  // 3 KiB

    const int tid  = threadIdx.x;
    const int lane = tid & 63;
    const int p    = lane >> 2;             // pair index 0..15
    const int q    = lane & 3;              // quarter 0..3
    const int wave = tid >> 6;              // 0..7
    const float4* cbv = (const float4*)cb;

    // B_k = np.sum(cb*cb, axis=-1), bit-exact
    for (int m = tid; m < kNcb * kK; m += kBlock)
        ((float*)s_B4)[m] = np_sumsq128(cb + (size_t)m * kDim);

    // items: 2 per 4-lane group, packed lo=A hi=B
    const size_t ia = (size_t)blockIdx.x * 256 + wave * 32 + p * 2 + 0;
    const size_t ib = ia + 1;
    const float4* xa4 = (const float4*)(x + ia * kDim + q * 32);
    const float4* xb4 = (const float4*)(x + ib * kDim + q * 32);

    PLIST(DECLP)
    ULIST(LOADU)

    float Aa, Ab;
    ACOMPUTE()

    int sA0=0,sA1=0,sA2=0,sB0=0,sB1=0,sB2=0;

    #pragma unroll
    for (int c = 0; c < kNcb; ++c) {
        float bestA = INFINITY, bestB = INFINITY;
        int   biA = 0, biB = 0;

        #pragma unroll
        for (int ph = 0; ph < 2; ++ph) {
            __syncthreads();   // previous phase fully consumed
            // stage 128 rows, quarter-interleaved: LDS[row*32 + jq*4 + qq]
            {
                const float4* gsrc = cbv + ((size_t)(c * kK + ph * 128)) * 32;
                #pragma unroll
                for (int u = 0; u < 8; ++u) {
                    const int gi  = u * kBlock + tid;        // coalesced
                    const float4 v = gsrc[gi];
                    const int row = gi >> 5, rem = gi & 31;
                    s_cb[row * 32 + (rem & 7) * 4 + (rem >> 3)] = v;
                }
            }
            __syncthreads();

            const int kbase = ph * 128;
            const int cb64  = c * 64 + ph * 32;
            f2v vm0={0.f,0.f}, vm1={0.f,0.f}, vm2={0.f,0.f}, vm3={0.f,0.f};

            #pragma unroll 1
            for (int g = 0; g < 35; ++g) {
                int gg = g - q; gg = gg < 0 ? 0 : (gg > 31 ? 31 : gg);
                const float4* tc = s_cb + gg * 128 + q;
                f2v m0 = q ? vm0 : (f2v){0.f,0.f}, m1 = q ? vm1 : (f2v){0.f,0.f},
                    m2 = q ? vm2 : (f2v){0.f,0.f}, m3 = q ? vm3 : (f2v){0.f,0.f};
                FOLD_U(0, PR0,PR1,PR2,PR3)
                FOLD_U(1, PR4,PR5,PR6,PR7)
                FOLD_U(2, PR8,PR9,PR10,PR11)
                FOLD_U(3, PR12,PR13,PR14,PR15)
                FOLD_U(4, PR16,PR17,PR18,PR19)
                FOLD_U(5, PR20,PR21,PR22,PR23)
                FOLD_U(6, PR24,PR25,PR26,PR27)
                FOLD_U(7, PR28,PR29,PR30,PR31)
                if (q == 3 && g >= 3) {                      // group g-3 final
                    const int gf = g - 3;
                    const float4 bb = s_B4[cb64 + gf];
                    const int kb = kbase + gf * 4;
                    float d_;
                    d_=(Aa-2.0f*m0.x)+bb.x; if(d_<bestA){bestA=d_;biA=kb+0;}
                    d_=(Aa-2.0f*m1.x)+bb.y; if(d_<bestA){bestA=d_;biA=kb+1;}
                    d_=(Aa-2.0f*m2.x)+bb.z; if(d_<bestA){bestA=d_;biA=kb+2;}
                    d_=(Aa-2.0f*m3.x)+bb.w; if(d_<bestA){bestA=d_;biA=kb+3;}
                    d_=(Ab-2.0f*m0.y)+bb.x; if(d_<bestB){bestB=d_;biB=kb+0;}
                    d_=(Ab-2.0f*m1.y)+bb.y; if(d_<bestB){bestB=d_;biB=kb+1;}
                    d_=(Ab-2.0f*m2.y)+bb.z; if(d_<bestB){bestB=d_;biB=kb+2;}
                    d_=(Ab-2.0f*m3.y)+bb.w; if(d_<bestB){bestB=d_;biB=kb+3;}
                }
                vm0.x=dpp_shr1(m0.x); vm0.y=dpp_shr1(m0.y);
                vm1.x=dpp_shr1(m1.x); vm1.y=dpp_shr1(m1.y);
                vm2.x=dpp_shr1(m2.x); vm2.y=dpp_shr1(m2.y);
                vm3.x=dpp_shr1(m3.x); vm3.y=dpp_shr1(m3.y);
            }
        }

        const int selA = __shfl(biA, lane | 3);   // broadcast from q==3
        const int selB = __shfl(biB, lane | 3);
        if (c == 0) { sA0 = selA; sB0 = selB; }
        else if (c == 1) { sA1 = selA; sB1 = selB; }
        else { sA2 = selA; sB2 = selB; }

        if (c < kNcb - 1) {   // residual -= q (elementwise, ref order); new A
            const float4* cwA = (const float4*)(cb + ((size_t)c*kK + selA)*kDim) + q*8;
            const float4* cwB = (const float4*)(cb + ((size_t)c*kK + selB)*kDim) + q*8;
            ULIST(SUBU)
            ACOMPUTE()
        }
    }

    // ---- outputs
    float* out_idx = out;                             // (items, 3) as float
    float* out_q   = out + (size_t)kItems * kNcb;     // (items, 128)
    if (q == 0) {
        out_idx[ia*3+0] = (float)sA0; out_idx[ia*3+1] = (float)sA1; out_idx[ia*3+2] = (float)sA2;
        out_idx[ib*3+0] = (float)sB0; out_idx[ib*3+1] = (float)sB1; out_idx[ib*3+2] = (float)sB2;
    }
    {
        const float4* g0 = (const float4*)(cb + ((size_t)0*kK + sA0)*kDim) + q*8;
        const float4* g1 = (const float4*)(cb + ((size_t)1*kK + sA1)*kDim) + q*8;
        const float4* g2 = (const float4*)(cb + ((size_t)2*kK + sA2)*kDim) + q*8;
        float4* qo = (float4*)(out_q + ia * kDim) + q*8;
        #pragma unroll
        for (int u = 0; u < 8; ++u) {
            const float4 v0 = g0[u], v1 = g1[u], v2 = g2[u];
            float4 w;
            w.x = (v0.x + v1.x) + v2.x; w.y = (v0.y + v1.y) + v2.y;
            w.z = (v0.z + v1.z) + v2.z; w.w = (v0.w + v1.w) + v2.w;
            qo[u] = w;                 // ((0+q0)+q1)+q2 in fp32, ref order
        }
    }
    {
        const float4* g0 = (const float4*)(cb + ((size_t)0*kK + sB0)*kDim) + q*8;
        const float4* g1 = (const float4*)(cb + ((size_t)1*kK + sB1)*kDim) + q*8;
        const float4* g2 = (const float4*)(cb + ((size_t)2*kK + sB2)*kDim) + q*8;
        float4* qo = (float4*)(out_q + ib * kDim) + q*8;
        #pragma unroll
        for (int u = 0; u < 8; ++u) {
            const float4 v0 = g0[u], v1 = g1[u], v2 = g2[u];
            float4 w;
            w.x = (v0.x + v1.x) + v2.x; w.y = (v0.y + v1.y) + v2.y;
            w.z = (v0.z + v1.z) + v2.z; w.w = (v0.w + v1.w) + v2.w;
            qo[u] = w;
        }
    }
}

extern "C" void kernel_launch(void* const* d_in, const int* in_sizes, int n_in,
                              void* d_out, int out_size, void* d_ws, size_t ws_size,
                              hipStream_t stream) {
    const float* x  = (const float*)d_in[0];
    const float* cb = (const float*)d_in[1];
    float* out = (float*)d_out;
    static bool attr_set = false;
    if (!attr_set) {
        hipFuncSetAttribute((const void*)rvq_kernel,
                            hipFuncAttributeMaxDynamicSharedMemorySize, 65536);
        attr_set = true;
    }
    rvq_kernel<<<kItems / 256, kBlock, 65536, stream>>>(x, cb, out);
}